// Round 21
// baseline (221.656 us; speedup 1.0000x reference)
//
#include <hip/hip_runtime.h>

#define NN 30000
#define EE 300000
#define HH 4
#define SLOPE 0.2f
#define SCAN_NB 15        // ceil(30000 / 2048)
#define SCB 293           // ceil(EE/4 / 256) scatter blocks per etype
#define HB 586            // 2 * ceil(EE/4 / 256) hist blocks total

typedef _Float16 f16;
typedef f16 f16x8 __attribute__((ext_vector_type(8)));
typedef float f32x4 __attribute__((ext_vector_type(4)));
typedef unsigned short u16;

// ---------------- zero deg (rocclr fill costs 43us; this is ~2us) ----------------
__global__ __launch_bounds__(256) void zero_k(int4* __restrict__ p, int n4) {
    const int i = blockIdx.x * 256 + threadIdx.x;
    if (i < n4) p[i] = make_int4(0, 0, 0, 0);
}

// ---------------- merged: W f16 transpose (blocks 0..47) || histogram (blocks 48..) --------
// Uniform per-block branch; hist needs only zeroed deg (zero_k runs before this kernel).
__global__ __launch_bounds__(256) void prep_hist_k(const float* __restrict__ W0,
                                                   const float* __restrict__ W1,
                                                   const float* __restrict__ W2,
                                                   f16* __restrict__ Wh,
                                                   const int* __restrict__ dst0,
                                                   const int* __restrict__ dst1,
                                                   int* __restrict__ deg) {
    if (blockIdx.x < 48) {
        const int l = blockIdx.x >> 4;          // layer 0..2
        const int t = (blockIdx.x >> 3) & 1;    // etype
        const int bx = blockIdx.x & 7;
        const float* W = (l == 0) ? W0 : ((l == 1) ? W1 : W2);
        f16* Whl = Wh + (size_t)l * 2 * 16384;
        const int i0 = bx * 2048;
        #pragma unroll
        for (int j = 0; j < 8; ++j) {
            const int i = i0 + threadIdx.x + j * 256;   // i = k*128 + col (coalesced read)
            const int k = i >> 7, col = i & 127;
            Whl[t * 16384 + col * 128 + k] = (f16)W[t * 16384 + i];
        }
        return;
    }
    // hist part: int4-vectorized, 4 edges/thread
    const int gi = (blockIdx.x - 48) * 256 + threadIdx.x;   // gi < 2*EE/4
    if (gi >= 2 * (EE / 4)) return;
    const int t = (gi >= EE / 4) ? 1 : 0;
    const int i = gi - t * (EE / 4);
    const int4 d = reinterpret_cast<const int4*>(t ? dst1 : dst0)[i];
    int* dg = deg + t * NN;
    atomicAdd(&dg[d.x], 1);
    atomicAdd(&dg[d.y], 1);
    atomicAdd(&dg[d.z], 1);
    atomicAdd(&dg[d.w], 1);
}

// ---------------- MFMA GEMM (layers 2,3): feat16[t][n][:] = Ah @ W[t], fused el/er ----------
#define APAD 136
__global__ __launch_bounds__(256) void gemm_mfma(const f16* __restrict__ Ah,
                                                 const float* __restrict__ Af,
                                                 const int use_f32,
                                                 const f16* __restrict__ Whbase,
                                                 const float* __restrict__ albase,
                                                 const float* __restrict__ arbase,
                                                 f16* __restrict__ featbase,
                                                 float* __restrict__ elbase,
                                                 float* __restrict__ erbase) {
    __shared__ f16 Bsl[128 * APAD];
    const int bx = blockIdx.x >> 1;
    const int et = blockIdx.x & 1;
    const f16* Wh = Whbase + et * 16384;
    f16* feat = featbase + (size_t)et * NN * 128;
    const int row0 = bx * 64;
    const int t = threadIdx.x;

    #pragma unroll
    for (int j = 0; j < 8; ++j) {
        const int idx = t + j * 256;            // idx = col*16 + k16
        const int col = idx >> 4, k16 = idx & 15;
        *reinterpret_cast<float4*>(&Bsl[col * APAD + k16 * 8]) =
            *reinterpret_cast<const float4*>(Wh + col * 128 + k16 * 8);
    }
    __syncthreads();

    const int w = t >> 6, lane = t & 63;
    const int r = lane & 15, g = lane >> 4;
    const int mb = w * 16;
    const int rowa = min(row0 + mb + r, NN - 1);
    f32x4 acc[8];
    #pragma unroll
    for (int nt = 0; nt < 8; ++nt) acc[nt] = (f32x4){0.f, 0.f, 0.f, 0.f};

    #pragma unroll
    for (int ks = 0; ks < 4; ++ks) {
        f16x8 av;
        if (use_f32) {
            const float4 a0 =
                *reinterpret_cast<const float4*>(Af + (size_t)rowa * 128 + ks * 32 + g * 8);
            const float4 a1 =
                *reinterpret_cast<const float4*>(Af + (size_t)rowa * 128 + ks * 32 + g * 8 + 4);
            av[0] = (f16)a0.x; av[1] = (f16)a0.y; av[2] = (f16)a0.z; av[3] = (f16)a0.w;
            av[4] = (f16)a1.x; av[5] = (f16)a1.y; av[6] = (f16)a1.z; av[7] = (f16)a1.w;
        } else {
            av = *reinterpret_cast<const f16x8*>(Ah + (size_t)rowa * 128 + ks * 32 + g * 8);
        }
        #pragma unroll
        for (int nt = 0; nt < 8; ++nt) {
            const f16x8 bv =
                *reinterpret_cast<const f16x8*>(&Bsl[(nt * 16 + r) * APAD + ks * 32 + g * 8]);
            acc[nt] = __builtin_amdgcn_mfma_f32_16x16x32_f16(av, bv, acc[nt], 0, 0, 0);
        }
    }

    float alv[8], arv[8];
    #pragma unroll
    for (int nt = 0; nt < 8; ++nt) {            // col = nt*16 + r
        alv[nt] = albase[et * 128 + nt * 16 + r];
        arv[nt] = arbase[et * 128 + nt * 16 + r];
    }
    #pragma unroll
    for (int p = 0; p < 4; ++p) {
        const int row = row0 + mb + g * 4 + p;
        const bool ok = row < NN;
        if (ok) {
            #pragma unroll
            for (int nt = 0; nt < 8; ++nt)
                feat[(size_t)row * 128 + nt * 16 + r] = (f16)acc[nt][p];
        }
        #pragma unroll
        for (int h = 0; h < 4; ++h) {
            float pl = fmaf(acc[2 * h][p], alv[2 * h], acc[2 * h + 1][p] * alv[2 * h + 1]);
            float pr = fmaf(acc[2 * h][p], arv[2 * h], acc[2 * h + 1][p] * arv[2 * h + 1]);
            pl += __shfl_xor(pl, 1); pl += __shfl_xor(pl, 2);
            pl += __shfl_xor(pl, 4); pl += __shfl_xor(pl, 8);
            pr += __shfl_xor(pr, 1); pr += __shfl_xor(pr, 2);
            pr += __shfl_xor(pr, 4); pr += __shfl_xor(pr, 8);
            if (ok && r == 0) {
                elbase[et * NN * HH + row * HH + h] = pl;
                erbase[et * NN * HH + row * HH + h] = pr;
            }
        }
    }
}

// ---------------- merged: scatter (blocks 0..2*SCB-1) || layer-1 gemm (rest) --------------
__global__ __launch_bounds__(256) void gemm1_scatter_k(const float* __restrict__ Af,
                                                       const f16* __restrict__ Whbase,
                                                       const float* __restrict__ albase,
                                                       const float* __restrict__ arbase,
                                                       f16* __restrict__ featbase,
                                                       float* __restrict__ elbase,
                                                       float* __restrict__ erbase,
                                                       const int* __restrict__ src0,
                                                       const int* __restrict__ dst0,
                                                       const int* __restrict__ src1,
                                                       const int* __restrict__ dst1,
                                                       int* __restrict__ cursor,
                                                       u16* __restrict__ csr_src) {
    __shared__ f16 Bsl[128 * APAD];
    if (blockIdx.x < 2 * SCB) {
        const int t = (blockIdx.x >= SCB) ? 1 : 0;
        const int i = (blockIdx.x - t * SCB) * 256 + threadIdx.x;
        if (i < EE / 4) {
            const int4 s = reinterpret_cast<const int4*>(t ? src1 : src0)[i];
            const int4 d = reinterpret_cast<const int4*>(t ? dst1 : dst0)[i];
            int* cur = cursor + t * NN;
            u16* cs = csr_src + t * EE;
            cs[atomicAdd(&cur[d.x], 1)] = (u16)s.x;
            cs[atomicAdd(&cur[d.y], 1)] = (u16)s.y;
            cs[atomicAdd(&cur[d.z], 1)] = (u16)s.z;
            cs[atomicAdd(&cur[d.w], 1)] = (u16)s.w;
        }
        return;
    }
    const int bxg = blockIdx.x - 2 * SCB;
    const int bx = bxg >> 1;
    const int et = bxg & 1;
    const f16* Wh = Whbase + et * 16384;
    f16* feat = featbase + (size_t)et * NN * 128;
    const int row0 = bx * 64;
    const int t = threadIdx.x;

    #pragma unroll
    for (int j = 0; j < 8; ++j) {
        const int idx = t + j * 256;
        const int col = idx >> 4, k16 = idx & 15;
        *reinterpret_cast<float4*>(&Bsl[col * APAD + k16 * 8]) =
            *reinterpret_cast<const float4*>(Wh + col * 128 + k16 * 8);
    }
    __syncthreads();

    const int w = t >> 6, lane = t & 63;
    const int r = lane & 15, g = lane >> 4;
    const int mb = w * 16;
    const int rowa = min(row0 + mb + r, NN - 1);
    f32x4 acc[8];
    #pragma unroll
    for (int nt = 0; nt < 8; ++nt) acc[nt] = (f32x4){0.f, 0.f, 0.f, 0.f};

    #pragma unroll
    for (int ks = 0; ks < 4; ++ks) {
        f16x8 av;
        {
            const float4 a0 =
                *reinterpret_cast<const float4*>(Af + (size_t)rowa * 128 + ks * 32 + g * 8);
            const float4 a1 =
                *reinterpret_cast<const float4*>(Af + (size_t)rowa * 128 + ks * 32 + g * 8 + 4);
            av[0] = (f16)a0.x; av[1] = (f16)a0.y; av[2] = (f16)a0.z; av[3] = (f16)a0.w;
            av[4] = (f16)a1.x; av[5] = (f16)a1.y; av[6] = (f16)a1.z; av[7] = (f16)a1.w;
        }
        #pragma unroll
        for (int nt = 0; nt < 8; ++nt) {
            const f16x8 bv =
                *reinterpret_cast<const f16x8*>(&Bsl[(nt * 16 + r) * APAD + ks * 32 + g * 8]);
            acc[nt] = __builtin_amdgcn_mfma_f32_16x16x32_f16(av, bv, acc[nt], 0, 0, 0);
        }
    }

    float alv[8], arv[8];
    #pragma unroll
    for (int nt = 0; nt < 8; ++nt) {
        alv[nt] = albase[et * 128 + nt * 16 + r];
        arv[nt] = arbase[et * 128 + nt * 16 + r];
    }
    #pragma unroll
    for (int p = 0; p < 4; ++p) {
        const int row = row0 + mb + g * 4 + p;
        const bool ok = row < NN;
        if (ok) {
            #pragma unroll
            for (int nt = 0; nt < 8; ++nt)
                feat[(size_t)row * 128 + nt * 16 + r] = (f16)acc[nt][p];
        }
        #pragma unroll
        for (int h = 0; h < 4; ++h) {
            float pl = fmaf(acc[2 * h][p], alv[2 * h], acc[2 * h + 1][p] * alv[2 * h + 1]);
            float pr = fmaf(acc[2 * h][p], arv[2 * h], acc[2 * h + 1][p] * arv[2 * h + 1]);
            pl += __shfl_xor(pl, 1); pl += __shfl_xor(pl, 2);
            pl += __shfl_xor(pl, 4); pl += __shfl_xor(pl, 8);
            pr += __shfl_xor(pr, 1); pr += __shfl_xor(pr, 2);
            pr += __shfl_xor(pr, 4); pr += __shfl_xor(pr, 8);
            if (ok && r == 0) {
                elbase[et * NN * HH + row * HH + h] = pl;
                erbase[et * NN * HH + row * HH + h] = pr;
            }
        }
    }
}

// ---------------- multi-block exclusive scan, phase 1 ----------------
__global__ __launch_bounds__(256) void scan1_k(const int* __restrict__ deg,
                                               int* __restrict__ offs,
                                               int* __restrict__ blocksum) {
    const int t = blockIdx.y, b = blockIdx.x;
    const int* d = deg + t * NN;
    int* o = offs + t * (NN + 1);
    const int base = b * 2048 + threadIdx.x * 8;
    int v[8];
    int s = 0;
    #pragma unroll
    for (int j = 0; j < 8; ++j) {
        const int i = base + j;
        v[j] = (i < NN) ? d[i] : 0;
        s += v[j];
    }
    __shared__ int buf[256];
    buf[threadIdx.x] = s;
    __syncthreads();
    #pragma unroll
    for (int ofs = 1; ofs < 256; ofs <<= 1) {
        const int add = (threadIdx.x >= (unsigned)ofs) ? buf[threadIdx.x - ofs] : 0;
        __syncthreads();
        buf[threadIdx.x] += add;
        __syncthreads();
    }
    int run = buf[threadIdx.x] - s;
    #pragma unroll
    for (int j = 0; j < 8; ++j) {
        const int i = base + j;
        if (i < NN) o[i] = run;
        run += v[j];
    }
    if (threadIdx.x == 255) blocksum[t * SCAN_NB + b] = buf[255];
}

// ---------------- scan phase 2+3 merged ----------------
__global__ __launch_bounds__(256) void scan3b_k(int* __restrict__ offs,
                                                const int* __restrict__ blocksum,
                                                int* __restrict__ cursor) {
    const int t = blockIdx.y, b = blockIdx.x;
    int boff = 0;
    #pragma unroll
    for (int i = 0; i < SCAN_NB; ++i)
        if (i < b) boff += blocksum[t * SCAN_NB + i];
    int* o = offs + t * (NN + 1);
    int* cur = cursor + t * NN;
    if (b == SCAN_NB - 1 && threadIdx.x == 0)
        o[NN] = boff + blocksum[t * SCAN_NB + SCAN_NB - 1];   // = EE
    const int base = b * 2048 + threadIdx.x * 8;
    #pragma unroll
    for (int j = 0; j < 8; ++j) {
        const int i = base + j;
        if (i < NN) {
            const int val = o[i] + boff;
            o[i] = val;
            cur[i] = val;
        }
    }
}

// ---------------- pull aggregate v12u: depth-4 index / depth-3 data pipeline (u16 csr) ------
__global__ __launch_bounds__(256) void pull_agg12_k(const u16* __restrict__ csr_src,
                                                    const int* __restrict__ offs,
                                                    const float* __restrict__ el,
                                                    const float* __restrict__ er,
                                                    const f16* __restrict__ feat,
                                                    const float* __restrict__ b0,
                                                    const float* __restrict__ b1,
                                                    f16* __restrict__ out, int relu) {
    __shared__ float xb[2][2][128];             // [node-parity][etype][col], normalized
    const int w = threadIdx.x >> 6, lane = threadIdx.x & 63;
    const int p = w >> 1, t = w & 1;
    const int n = blockIdx.x * 2 + p;           // NN even
    const int sub = lane >> 4;                  // edge slot within quad (0..3)
    const int cg = lane & 15;                   // col group
    const int h = cg >> 2;                      // head
    const int c0 = cg * 8;

    const int* so = offs + t * (NN + 1);
    const int e0 = so[n], e1 = so[n + 1];

    float s = 0.f;
    float x[8];
    #pragma unroll
    for (int j = 0; j < 8; ++j) x[j] = 0.f;

    if (e0 < e1) {
        const u16* cs = csr_src + t * EE;
        const float* elt = el + t * NN * HH;
        const float erh = er[t * NN * HH + n * HH + h];
        const f16* ft = feat + (size_t)t * NN * 128;
        const int elast = e1 - 1;

        int si_0 = cs[min(e0 + sub, elast)];
        int si_1 = cs[min(e0 + 4 + sub, elast)];
        int si_2 = cs[min(e0 + 8 + sub, elast)];
        int si_3 = cs[min(e0 + 12 + sub, elast)];
        float lv_0 = elt[si_0 * HH + h];
        f16x8 fr_0 = *reinterpret_cast<const f16x8*>(ft + (size_t)si_0 * 128 + c0);
        float lv_1 = elt[si_1 * HH + h];
        f16x8 fr_1 = *reinterpret_cast<const f16x8*>(ft + (size_t)si_1 * 128 + c0);
        float lv_2 = elt[si_2 * HH + h];
        f16x8 fr_2 = *reinterpret_cast<const f16x8*>(ft + (size_t)si_2 * 128 + c0);

        for (int eb = e0; eb < e1; eb += 4) {
            const int si_4 = cs[min(eb + 16 + sub, elast)];       // index for quad q+4
            const float lv_3 = elt[si_3 * HH + h];                // data for quad q+3
            const f16x8 fr_3 = *reinterpret_cast<const f16x8*>(ft + (size_t)si_3 * 128 + c0);
            float v = lv_0 + erh;                                  // compute quad q
            v = (v >= 0.f) ? v : v * SLOPE;
            float ex = __expf(v);
            ex = (eb + sub < e1) ? ex : 0.f;
            s += ex;
            #pragma unroll
            for (int j = 0; j < 8; ++j) x[j] = fmaf(ex, (float)fr_0[j], x[j]);
            lv_0 = lv_1; fr_0 = fr_1;
            lv_1 = lv_2; fr_1 = fr_2;
            lv_2 = lv_3; fr_2 = fr_3;
            si_3 = si_4;
        }
    }

    s += __shfl_xor(s, 16); s += __shfl_xor(s, 32);
    #pragma unroll
    for (int j = 0; j < 8; ++j) {
        x[j] += __shfl_xor(x[j], 16);
        x[j] += __shfl_xor(x[j], 32);
    }
    const float inv = (s > 0.f) ? 1.f / s : 0.f;    // isolated node -> 0, matches ref
    if (sub == 0) {
        float4 v0 = make_float4(x[0] * inv, x[1] * inv, x[2] * inv, x[3] * inv);
        float4 v1 = make_float4(x[4] * inv, x[5] * inv, x[6] * inv, x[7] * inv);
        *reinterpret_cast<float4*>(&xb[p][t][c0]) = v0;
        *reinterpret_cast<float4*>(&xb[p][t][c0 + 4]) = v1;
    }
    __syncthreads();
    if (t == 0) {
        const int c = lane * 2;
        float a0 = xb[p][0][c] + xb[p][1][c] + b0[c] + b1[c];
        float a1 = xb[p][0][c + 1] + xb[p][1][c + 1] + b0[c + 1] + b1[c + 1];
        if (relu) { a0 = fmaxf(a0, 0.f); a1 = fmaxf(a1, 0.f); }
        union { f16 h2[2]; float f; } o;
        o.h2[0] = (f16)a0; o.h2[1] = (f16)a1;
        *reinterpret_cast<float*>(out + (size_t)n * 128 + c) = o.f;
    }
}

// ---------------- final linear (f16 input) ----------------
__global__ __launch_bounds__(256) void out_gemm_k(const f16* __restrict__ A,
                                                  const float* __restrict__ W,
                                                  const float* __restrict__ bout,
                                                  float* __restrict__ out) {
    __shared__ float At[16][132];
    const int row0 = blockIdx.x * 16;   // NN % 16 == 0
    const int t = threadIdx.x;
    {
        const int r = t >> 4, c8 = t & 15;
        const f16x8 v = *reinterpret_cast<const f16x8*>(A + (size_t)(row0 + r) * 128 + c8 * 8);
        #pragma unroll
        for (int j = 0; j < 8; ++j) At[r][c8 * 8 + j] = (float)v[j];
    }
    __syncthreads();
    const int r = t >> 4, c = t & 15;
    float accv = 0.f;
    #pragma unroll 8
    for (int k = 0; k < 128; ++k) accv = fmaf(At[r][k], W[k * 16 + c], accv);
    out[(row0 + r) * 16 + c] = accv + bout[c];
}

extern "C" void kernel_launch(void* const* d_in, const int* in_sizes, int n_in,
                              void* d_out, int out_size, void* d_ws, size_t ws_size,
                              hipStream_t stream) {
    (void)in_sizes; (void)n_in; (void)out_size; (void)ws_size;
    const float* x = (const float*)d_in[0];
    const int* src0 = (const int*)d_in[1];
    const int* dst0 = (const int*)d_in[2];
    const int* src1 = (const int*)d_in[3];
    const int* dst1 = (const int*)d_in[4];
    const float* W[3]  = {(const float*)d_in[5], (const float*)d_in[9],  (const float*)d_in[13]};
    const float* al[3] = {(const float*)d_in[6], (const float*)d_in[10], (const float*)d_in[14]};
    const float* ar[3] = {(const float*)d_in[7], (const float*)d_in[11], (const float*)d_in[15]};
    const float* bb[3] = {(const float*)d_in[8], (const float*)d_in[12], (const float*)d_in[16]};
    const float* Wout = (const float*)d_in[17];
    const float* bout = (const float*)d_in[18];
    float* outp = (float*)d_out;

    char* pb = (char*)d_ws;
    f16* feat   = (f16*)pb;    pb += (size_t)2 * NN * 128 * 2;   // [2][NN][128] fp16
    f16* hbuf   = (f16*)pb;    pb += (size_t)NN * 128 * 2;
    float* el   = (float*)pb;  pb += (size_t)2 * NN * HH * 4;
    float* er   = (float*)pb;  pb += (size_t)2 * NN * HH * 4;
    int* deg    = (int*)pb;    pb += (size_t)2 * NN * 4;
    int* cursor = (int*)pb;    pb += (size_t)2 * NN * 4;
    int* offs   = (int*)pb;    pb += (size_t)2 * (NN + 1) * 4;
    int* bsum   = (int*)pb;    pb += (size_t)2 * SCAN_NB * 4;
    f16* Wh     = (f16*)pb;    pb += (size_t)3 * 2 * 128 * 128 * 2;
    u16* csr    = (u16*)pb;    pb += (size_t)2 * EE * 2;

    // ---- setup: zero deg; W convert || histogram; scans; scatter || gemm-1 ----
    zero_k<<<(2 * NN / 4 + 255) / 256, 256, 0, stream>>>((int4*)deg, 2 * NN / 4);
    prep_hist_k<<<48 + HB, 256, 0, stream>>>(W[0], W[1], W[2], Wh, dst0, dst1, deg);
    scan1_k<<<dim3(SCAN_NB, 2), 256, 0, stream>>>(deg, offs, bsum);
    scan3b_k<<<dim3(SCAN_NB, 2), 256, 0, stream>>>(offs, bsum, cursor);
    gemm1_scatter_k<<<2 * SCB + 938, 256, 0, stream>>>(x, Wh, al[0], ar[0], feat, el, er,
                                                       src0, dst0, src1, dst1, cursor, csr);

    // ---- layer-1 pull, then layers 2,3 ----
    pull_agg12_k<<<NN / 2, 256, 0, stream>>>(csr, offs, el, er, feat,
                                             bb[0], bb[0] + 128, hbuf, 1);
    for (int l = 1; l < 3; ++l) {
        gemm_mfma<<<938, 256, 0, stream>>>(
            hbuf, x, 0, Wh + l * 2 * 16384, al[l], ar[l], feat, el, er);
        pull_agg12_k<<<NN / 2, 256, 0, stream>>>(csr, offs, el, er, feat,
                                                 bb[l], bb[l] + 128, hbuf, (l < 2) ? 1 : 0);
    }
    out_gemm_k<<<NN / 16, 256, 0, stream>>>(hbuf, Wout, bout, outp);
}